// Round 3
// baseline (122.382 us; speedup 1.0000x reference)
//
#include <hip/hip_runtime.h>
#include <math.h>

#define D 768
#define T 128
#define KC 16            // split-K chunks for GEMM1
#define CHUNKK (D / KC)  // 48
#define NSUB (CHUNKK / 16) // 3 sub-chunks of 16
#define NBLK 192

// ln(0.9*0.99) = ln(0.891)
#define LN_ETA_DECAY (-0.11541085151132775f)

// ---------------------------------------------------------------------------
// Single REGULAR-launch kernel (graph-capturable), 192 blocks x 512 threads,
// 3 phases separated by a hand-rolled device-scope spin barrier:
//   P1: split-K partial GEMM  P = keys @ W^T      (all 192 blocks)
//   P2: errW = sum_kc Ppart - values              (all 192 blocks)
//   P3: GEMM2 + fused W/mW/b/losses epilogue      (144 of 192 blocks)
// Deadlock-safe: 192 blocks <= 256 CUs, 66KB LDS -> all co-resident.
// Barrier counters live at d_ws[0..1], zeroed by an in-stream hipMemsetAsync
// (workspace is re-poisoned every iteration, so counters can't persist).
// ---------------------------------------------------------------------------

union SharedU {
    struct {
        float sKt[16][132];  // [k][t], pitch 132
        float sWo[16][68];   // [k][o], pitch 68
    } p1;
    struct {
        float sErr[T][64];   // errW[t, o-local]
        float sKs[T][64];    // 2*c[t]*keys[t, i-local]
        float sC[T];         // c[t]
        float sB0[64];       // bparam[o-local]
    } p3;
};

__device__ __forceinline__ void grid_barrier(int* bar, int tid) {
    __syncthreads();                 // block's prior work complete
    if (tid == 0) {
        __threadfence();             // release: make global writes visible
        __hip_atomic_fetch_add(bar, 1, __ATOMIC_RELEASE, __HIP_MEMORY_SCOPE_AGENT);
        while (__hip_atomic_load(bar, __ATOMIC_ACQUIRE, __HIP_MEMORY_SCOPE_AGENT) < NBLK)
            __builtin_amdgcn_s_sleep(1);
        __threadfence();             // acquire: invalidate stale cached lines
    }
    __syncthreads();
}

__global__ __launch_bounds__(512) void fused_all(
    const float* __restrict__ W,
    const float* __restrict__ keys,
    const float* __restrict__ values,
    const float* __restrict__ mW,
    const float* __restrict__ bparam,
    const float* __restrict__ mb,
    float* __restrict__ W_new,
    float* __restrict__ b_new,
    float* __restrict__ mW_new,
    float* __restrict__ mb_new,
    float* __restrict__ losses,
    int* __restrict__ bar,
    float* __restrict__ Ppart,
    float* __restrict__ errW,
    float pow_eta_T, float beta_total, float Csum)
{
    __shared__ SharedU sh;
    const int b = blockIdx.x;
    const int tid = threadIdx.x;

    // =====================================================================
    // Phase 1: split-K partial GEMM (all 192 blocks), 4t x 4o per thread
    // =====================================================================
    {
        float (&sKt)[16][132] = sh.p1.sKt;
        float (&sWo)[16][68]  = sh.p1.sWo;

        const int bx = b / KC;          // o-tile 0..11
        const int by = b % KC;          // k-chunk 0..15
        const int obase = bx * 64;
        const int kbase = by * CHUNKK;
        const int ty = tid >> 4;   // t-group (4 t's), 0..31
        const int tx = tid & 15;   // o-group (4 o's)
        const int t0 = tid >> 2;   // keys staging row (0..127)
        const int q0 = tid & 3;    // staging float4-col (0..3)
        const int o0 = (tid >> 2) & 63; // W staging row for tid<256

        if (b == 0 && tid < T) losses[tid] = 0.f;

        float acc[4][4];
        #pragma unroll
        for (int j = 0; j < 4; ++j)
            #pragma unroll
            for (int n = 0; n < 4; ++n) acc[j][n] = 0.f;

        float4 gk = *reinterpret_cast<const float4*>(keys + t0 * D + kbase + q0 * 4);
        float4 gw;
        if (tid < 256)
            gw = *reinterpret_cast<const float4*>(W + (obase + o0) * D + kbase + q0 * 4);

        for (int c = 0; c < NSUB; ++c) {
            sKt[q0 * 4 + 0][t0] = gk.x;
            sKt[q0 * 4 + 1][t0] = gk.y;
            sKt[q0 * 4 + 2][t0] = gk.z;
            sKt[q0 * 4 + 3][t0] = gk.w;
            if (tid < 256) {
                sWo[q0 * 4 + 0][o0] = gw.x;
                sWo[q0 * 4 + 1][o0] = gw.y;
                sWo[q0 * 4 + 2][o0] = gw.z;
                sWo[q0 * 4 + 3][o0] = gw.w;
            }
            __syncthreads();

            if (c + 1 < NSUB) {
                const int kb = kbase + (c + 1) * 16;
                gk = *reinterpret_cast<const float4*>(keys + t0 * D + kb + q0 * 4);
                if (tid < 256)
                    gw = *reinterpret_cast<const float4*>(W + (obase + o0) * D + kb + q0 * 4);
            }

            #pragma unroll
            for (int k = 0; k < 16; ++k) {
                float4 a = *reinterpret_cast<const float4*>(&sKt[k][ty * 4]);
                float4 bb = *reinterpret_cast<const float4*>(&sWo[k][tx * 4]);
                const float av[4] = { a.x, a.y, a.z, a.w };
                const float bv[4] = { bb.x, bb.y, bb.z, bb.w };
                #pragma unroll
                for (int j = 0; j < 4; ++j)
                    #pragma unroll
                    for (int n = 0; n < 4; ++n) acc[j][n] += av[j] * bv[n];
            }
            __syncthreads();
        }

        float* outp = Ppart + by * (T * D);
        #pragma unroll
        for (int j = 0; j < 4; ++j) {
            const int t = ty * 4 + j;
            float4 v = { acc[j][0], acc[j][1], acc[j][2], acc[j][3] };
            *reinterpret_cast<float4*>(outp + t * D + obase + tx * 4) = v;
        }
    }

    grid_barrier(bar, tid);

    // =====================================================================
    // Phase 2: errW = sum_kc Ppart[kc] - values
    // 192 blocks, threads 0..127 each one float4: 192*128 = 24576 = T*D/4
    // =====================================================================
    if (tid < 128) {
        const int off = (b * 128 + tid) * 4;
        float4 vv = *reinterpret_cast<const float4*>(values + off);
        float4 s = { -vv.x, -vv.y, -vv.z, -vv.w };
        #pragma unroll
        for (int kc = 0; kc < KC; ++kc) {
            float4 v = *reinterpret_cast<const float4*>(Ppart + kc * (T * D) + off);
            s.x += v.x; s.y += v.y; s.z += v.z; s.w += v.w;
        }
        *reinterpret_cast<float4*>(errW + off) = s;
    }

    grid_barrier(bar + 1, tid);

    // =====================================================================
    // Phase 3: GEMM2 G = errW^T @ (2c*keys) + fused epilogue (144 blocks),
    // 512 threads: per-thread output tile 2o x 4i.
    // =====================================================================
    if (b < 144) {
        float (&sErr)[T][64] = sh.p3.sErr;
        float (&sKs)[T][64]  = sh.p3.sKs;
        float (&sC)[T]       = sh.p3.sC;
        float (&sB0)[64]     = sh.p3.sB0;

        const int oT = b / 12, iT = b % 12;
        const int obase = oT * 64, ibase = iT * 64;
        const int ty = tid >> 4;   // 0..31, owns o-pair ty*2
        const int tx = tid & 15;   // i-quad

        // epilogue prefetch: issue mW/W loads now, consume after GEMM2
        float4 pm[2], pw[2];
        #pragma unroll
        for (int aa = 0; aa < 2; ++aa) {
            const int o = obase + ty * 2 + aa;
            const int i = ibase + tx * 4;
            pm[aa] = *reinterpret_cast<const float4*>(mW + o * D + i);
            pw[aa] = *reinterpret_cast<const float4*>(W + o * D + i);
        }

        if (tid < T)  sC[tid]  = 0.01f * __expf((float)(127 - tid) * LN_ETA_DECAY);
        if (tid < 64) sB0[tid] = bparam[obase + tid];

        // stage sErr and sKs = 2*c[t]*keys[t, i-tile]
        #pragma unroll
        for (int p = 0; p < 4; ++p) {
            const int idx = tid + p * 512;
            const int t = idx >> 4, q = idx & 15;
            float4 ev = *reinterpret_cast<const float4*>(errW + t * D + obase + q * 4);
            *reinterpret_cast<float4*>(&sErr[t][q * 4]) = ev;

            const float c2 = 2.f * 0.01f * __expf((float)(127 - t) * LN_ETA_DECAY);
            float4 kv = *reinterpret_cast<const float4*>(keys + t * D + ibase + q * 4);
            kv.x *= c2; kv.y *= c2; kv.z *= c2; kv.w *= c2;
            *reinterpret_cast<float4*>(&sKs[t][q * 4]) = kv;
        }
        __syncthreads();

        float acc[2][4];
        #pragma unroll
        for (int a = 0; a < 2; ++a)
            #pragma unroll
            for (int n = 0; n < 4; ++n) acc[a][n] = 0.f;

        #pragma unroll 4
        for (int t = 0; t < T; ++t) {
            float2 a = *reinterpret_cast<const float2*>(&sErr[t][ty * 2]);
            float4 bb = *reinterpret_cast<const float4*>(&sKs[t][tx * 4]);
            const float av[2] = { a.x, a.y };
            const float bv[4] = { bb.x, bb.y, bb.z, bb.w };
            #pragma unroll
            for (int aa = 0; aa < 2; ++aa)
                #pragma unroll
                for (int nn = 0; nn < 4; ++nn) acc[aa][nn] += av[aa] * bv[nn];
        }

        // W / mW epilogue from prefetched regs
        #pragma unroll
        for (int aa = 0; aa < 2; ++aa) {
            const int o = obase + ty * 2 + aa;
            const int i = ibase + tx * 4;
            float4 nm, wn;
            nm.x = pow_eta_T * pm[aa].x - acc[aa][0];
            nm.y = pow_eta_T * pm[aa].y - acc[aa][1];
            nm.z = pow_eta_T * pm[aa].z - acc[aa][2];
            nm.w = pow_eta_T * pm[aa].w - acc[aa][3];
            wn.x = beta_total * pw[aa].x + nm.x;
            wn.y = beta_total * pw[aa].y + nm.y;
            wn.z = beta_total * pw[aa].z + nm.z;
            wn.w = beta_total * pw[aa].w + nm.w;
            *reinterpret_cast<float4*>(mW_new + o * D + i) = nm;
            *reinterpret_cast<float4*>(W_new + o * D + i) = wn;
        }

        // b epilogue (once per o-tile)
        if (iT == 0 && tid < 64) {
            float S = 0.f;
            for (int t = 0; t < T; ++t) S += sC[t] * sErr[t][tid];
            const int o = obase + tid;
            const float nmb = pow_eta_T * mb[o] - 2.f * S - 2.f * Csum * sB0[tid];
            mb_new[o] = nmb;
            b_new[o]  = beta_total * sB0[tid] + nmb;
        }

        // losses partial (once per o-tile); losses zeroed in phase 1
        if (iT == 1 && tid < 256) {
            const int t = tid >> 1, h = tid & 1;
            float L = 0.f;
            #pragma unroll 8
            for (int oo = 0; oo < 32; ++oo) {
                const int o = ((h * 32 + oo) + t) & 63;   // skew to dodge bank aliasing
                const float e = sErr[t][o] + sB0[o];
                L += e * e;
            }
            L += __shfl_xor(L, 1, 64);
            if (h == 0) atomicAdd(losses + t, L * (1.f / 768.f));
        }
    }
}

extern "C" void kernel_launch(void* const* d_in, const int* in_sizes, int n_in,
                              void* d_out, int out_size, void* d_ws, size_t ws_size,
                              hipStream_t stream) {
    const float* W      = (const float*)d_in[0];
    const float* bparam = (const float*)d_in[1];
    const float* keys   = (const float*)d_in[2];
    const float* values = (const float*)d_in[3];
    const float* mW     = (const float*)d_in[4];
    const float* mb     = (const float*)d_in[5];

    float* out = (float*)d_out;
    float* W_new  = out;               // 768*768
    float* b_new  = out + 589824;      // 768
    float* mW_new = out + 590592;      // 768*768
    float* mb_new = out + 1180416;     // 768
    float* losses = out + 1181184;     // 128

    int*   bar   = (int*)d_ws;                   // 2 counters (256 B reserved)
    float* Ppart = (float*)d_ws + 64;            // KC*T*D floats = 6.3 MB
    float* errW  = Ppart + KC * T * D;           // T*D floats

    double cs = 0.0;
    for (int t = 0; t < T; ++t) cs += 0.01 * pow(0.891, 127 - t);
    const float pow_eta_T  = (float)pow(0.9, 128);
    const float beta_total = (float)pow(0.99, 128);
    const float Csum = (float)cs;

    // barrier counters start poisoned each iteration -> zero them in-stream
    hipMemsetAsync(d_ws, 0, 256, stream);
    fused_all<<<NBLK, 512, 0, stream>>>(W, keys, values, mW, bparam, mb,
                                        W_new, b_new, mW_new, mb_new, losses,
                                        bar, Ppart, errW,
                                        pow_eta_T, beta_total, Csum);
}